// Round 7
// baseline (250.604 us; speedup 1.0000x reference)
//
#include <hip/hip_runtime.h>
#include <hip/hip_cooperative_groups.h>
#include <stdint.h>

namespace cg = cooperative_groups;

#define NROWS 2048
#define DDIM  9216
#define TILE  160
#define KS    8                       // K-slices
#define KSLEN 1152                    // DDIM/KS
#define BK    64                      // K-step per stage
#define KIT   18                      // KSLEN/BK
#define GRID  256                     // 1 block/CU, cooperative co-residency

typedef unsigned short u16;
typedef __bf16 bf16x8 __attribute__((ext_vector_type(8)));
typedef float  f32x4  __attribute__((ext_vector_type(4)));

// ws layout: [0..1088) meta: [0] int A (unused now, kept), [64..1088) bsum[256]
//            [4096..) u16 nf[2048][9216]                    (37.75 MB)
//            [P_OFF..) float P[ntri][8][4][6400] partials   (74.5 MB max)
#define NF_OFF 4096ull
#define P_OFF  (NF_OFF + 2048ull * 9216ull * 2ull)

__device__ __forceinline__ u16 f2bf(float f) {
    uint32_t x = __float_as_uint(f);
    x += 0x7fffu + ((x >> 16) & 1u);          // round-to-nearest-even
    return (u16)(x >> 16);
}

__device__ __forceinline__ void gload16(const u16* g, u16* l) {
    __builtin_amdgcn_global_load_lds(
        (const __attribute__((address_space(1))) uint32_t*)g,
        (__attribute__((address_space(3))) uint32_t*)l, 16, 0, 0);
}

// ---------------- gemm core: identical to R6 (verified) ----------------
template<bool DIAG>
__device__ __forceinline__ void stage(const u16* pA, const u16* pB, int kt,
                                      u16* buf, int w) {
    const u16* a = pA + kt * BK;
    u16* Ad = buf + w * 2560;                 // 40 rows x 64 u16 per wave
#pragma unroll
    for (int i = 0; i < 5; ++i)
        gload16(a + (size_t)(8 * i) * DDIM, Ad + i * 512);
    if (!DIAG) {
        const u16* b = pB + kt * BK;
        u16* Bd = buf + 10240 + w * 2560;     // B half of the stage buffer
#pragma unroll
        for (int i = 0; i < 5; ++i)
            gload16(b + (size_t)(8 * i) * DDIM, Bd + i * 512);
    }
}

template<bool DIAG>
__device__ __forceinline__ void compute(const u16* buf, int wr, int wc,
                                        int m16, int quad, f32x4 acc[5][5]) {
    const u16* Ab = buf;
    const u16* Bb = DIAG ? buf : buf + 10240;
#pragma unroll
    for (int kk = 0; kk < 2; ++kk) {
        int sw = ((((kk << 2) | quad) ^ (m16 & 7)) << 3);
        bf16x8 af[5], bfr[5];
#pragma unroll
        for (int fm = 0; fm < 5; ++fm)
            af[fm] = *(const bf16x8*)&Ab[(wr * 80 + fm * 16 + m16) * 64 + sw];
#pragma unroll
        for (int fn = 0; fn < 5; ++fn)
            bfr[fn] = *(const bf16x8*)&Bb[(wc * 80 + fn * 16 + m16) * 64 + sw];
#pragma unroll
        for (int fm = 0; fm < 5; ++fm)
#pragma unroll
            for (int fn = 0; fn < 5; ++fn)
                acc[fm][fn] = __builtin_amdgcn_mfma_f32_16x16x32_bf16(
                    af[fm], bfr[fn], acc[fm][fn], 0, 0, 0);
    }
}

__device__ __forceinline__ void barrier_fenced() {
    asm volatile("" ::: "memory");
    __builtin_amdgcn_s_barrier();
    asm volatile("" ::: "memory");
}

template<bool DIAG, bool PRE, int VM>
__device__ __forceinline__ void kstep(const u16* pA, const u16* pB, int kt,
                                      u16* bufC, u16* bufT, int w, int wr, int wc,
                                      int m16, int quad, bool dead, f32x4 acc[5][5]) {
    __builtin_amdgcn_s_waitcnt(VM);
    barrier_fenced();
    if (PRE) stage<DIAG>(pA, pB, kt + 2, bufT, w);
    if (!dead) compute<DIAG>(bufC, wr, wc, m16, quad, acc);
}

template<bool DIAG>
__device__ __forceinline__ void kloop(const u16* pA, const u16* pB, u16* ls,
                                      int w, int wr, int wc, int m16, int quad,
                                      bool dead, f32x4 acc[5][5]) {
    u16* b0 = ls;                             // 40 KB per stage buffer
    u16* b1 = ls + 20480;
    u16* b2 = ls + 40960;
    constexpr int VMF = DIAG ? 0x0F75 : 0x0F7A;   // vmcnt(5) / vmcnt(10)
    stage<DIAG>(pA, pB, 0, b0, w);
    stage<DIAG>(pA, pB, 1, b1, w);
    for (int kt = 0; kt < KIT - 3; kt += 3) {
        kstep<DIAG, true, VMF>(pA, pB, kt,     b0, b2, w, wr, wc, m16, quad, dead, acc);
        kstep<DIAG, true, VMF>(pA, pB, kt + 1, b1, b0, w, wr, wc, m16, quad, dead, acc);
        kstep<DIAG, true, VMF>(pA, pB, kt + 2, b2, b1, w, wr, wc, m16, quad, dead, acc);
    }
    kstep<DIAG, true,  VMF   >(pA, pB, KIT - 3, b0, b2, w, wr, wc, m16, quad, dead, acc);
    kstep<DIAG, false, VMF   >(pA, pB, KIT - 2, b1, b0, w, wr, wc, m16, quad, dead, acc);
    kstep<DIAG, false, 0x0F70>(pA, pB, KIT - 1, b2, b1, w, wr, wc, m16, quad, dead, acc);
}

// ---------------- single cooperative mega-kernel ----------------
__global__ __launch_bounds__(256) void mega_kernel(const float* __restrict__ wgt,
                                                   const float* __restrict__ mask,
                                                   u16* __restrict__ nf,
                                                   float* __restrict__ meta,
                                                   float* __restrict__ P,
                                                   float* __restrict__ out) {
    __shared__ __align__(16) u16 ls[61440];   // 120 KB, reused by every phase
    cg::grid_group gg = cg::this_grid();
    int bid = blockIdx.x, tid = threadIdx.x;
    int w = tid >> 6, l = tid & 63;

    // ======== phase 1: mask census (atomic-free compaction) + stats ========
    int* mcnt = (int*)ls;                     // 256 ints
    float* rsh = (float*)(ls + 2048);         // byte offset 4096: rs[4],rss[4],mean,inv
    {
        const float* mp = mask + tid * 8;     // thread t censuses rows [8t, 8t+8)
        int c8 = 0;
#pragma unroll
        for (int r = 0; r < 8; ++r) c8 += (mp[r] != 0.0f) ? 1 : 0;
        mcnt[tid] = c8;
    }
    __syncthreads();
    int pre = 0, Atot = 0;                    // prefix before this block's rows; total
    for (int j = 0; j < 256; ++j) {
        int v = mcnt[j];
        if (j < bid) pre += v;
        Atot += v;
    }
    __syncthreads();                          // mcnt dead; rsh reused below
    int slot = pre;
    for (int r = 0; r < 8; ++r) {             // this block owns rows 8*bid..8*bid+7
        int n = bid * 8 + r;
        if (mask[n] == 0.0f) continue;        // block-uniform branch: syncs safe
        const float4* row = (const float4*)(wgt + (size_t)n * DDIM);
        float4 v[9];
        float s = 0.f, ss = 0.f;
#pragma unroll
        for (int i = 0; i < 9; ++i) {
            v[i] = row[tid + 256 * i];
            s  += v[i].x + v[i].y + v[i].z + v[i].w;
            ss += v[i].x * v[i].x + v[i].y * v[i].y + v[i].z * v[i].z + v[i].w * v[i].w;
        }
#pragma unroll
        for (int o = 32; o > 0; o >>= 1) { s += __shfl_down(s, o); ss += __shfl_down(ss, o); }
        if (l == 0) { rsh[w] = s; rsh[4 + w] = ss; }
        __syncthreads();
        if (tid == 0) {
            float S  = rsh[0] + rsh[1] + rsh[2] + rsh[3];
            float SS = rsh[4] + rsh[5] + rsh[6] + rsh[7];
            float mean = S / (float)DDIM;
            float var  = SS / (float)DDIM - mean * mean;
            float sd   = sqrtf(fmaxf(var, 0.f));
            if (sd == 0.f) sd = 1.f;          // reference: std==0 -> 1
            rsh[8] = mean; rsh[9] = 1.f / sd;
        }
        __syncthreads();
        float mean = rsh[8], inv = rsh[9];
        u16* dst = nf + (size_t)slot * DDIM;
#pragma unroll
        for (int i = 0; i < 9; ++i) {
            int e = (tid + 256 * i) * 4;
            uint32_t lo = (uint32_t)f2bf((v[i].x - mean) * inv) |
                          ((uint32_t)f2bf((v[i].y - mean) * inv) << 16);
            uint32_t hi = (uint32_t)f2bf((v[i].z - mean) * inv) |
                          ((uint32_t)f2bf((v[i].w - mean) * inv) << 16);
            uint2 u; u.x = lo; u.y = hi;
            *(uint2*)(dst + e) = u;
        }
        ++slot;
    }

    gg.sync();                                // nf complete, visible grid-wide

    // ======== phase 2: 160x160-tile partial GEMM, K-split by 8 (R6 core) ========
    int A = Atot;
    int nt = (A + TILE - 1) / TILE;
    int ntri = nt * (nt + 1) >> 1;
    int quad = l >> 4, m16 = l & 15;
    int wr = w >> 1, wc = w & 1;
    int colsw = ((l & 7) ^ (l >> 3)) << 3;    // pre-swizzled global col chunk
    for (int tk = bid; tk < ntri * 8; tk += GRID) {   // GRID%8==0 keeps k fixed
        int t = tk >> 3, k = tk & 7;
        int tt = t, bi = 0, len = nt;
        while (tt >= len) { tt -= len; --len; ++bi; }
        int bj = bi + tt;                     // bi <= bj
        int r0 = bi * TILE, c0 = bj * TILE;
        size_t kbase = (size_t)k * KSLEN + colsw;
        const u16* pA = nf + (size_t)(r0 + 40 * w + (l >> 3)) * DDIM + kbase;
        const u16* pB = nf + (size_t)(c0 + 40 * w + (l >> 3)) * DDIM + kbase;
        bool dead = (bi == bj) && (w == 2);   // diag sub-block, all gi>gj
        f32x4 acc[5][5] = {};
        if (bi == bj) kloop<true >(pA, pB, ls, w, wr, wc, m16, quad, dead, acc);
        else          kloop<false>(pA, pB, ls, w, wr, wc, m16, quad, dead, acc);
        float* dst = P + ((size_t)(t * 8 + k) * 4 + w) * 6400;
#pragma unroll
        for (int fm = 0; fm < 5; ++fm)
#pragma unroll
            for (int fn = 0; fn < 5; ++fn)
                *(f32x4*)&dst[(fm * 5 + fn) * 256 + l * 4] = acc[fm][fn];
    }

    gg.sync();                                // P complete, visible grid-wide

    // ======== phase 3: reduce 8 k-partials, square, mask, per-block sum ========
    float local = 0.f;
    for (int x = bid; x < ntri * 4; x += GRID) {
        int t = x >> 2, c = x & 3;
        int tt = t, bi = 0, len = nt;
        while (tt >= len) { tt -= len; --len; ++bi; }
        int bj = bi + tt;
        int r0 = bi * TILE, c0 = bj * TILE;
        const float* base = P + (size_t)t * 204800 + (size_t)c * 6400;
#pragma unroll
        for (int mm = 0; mm < 7; ++mm) {
            int idx = mm * 256 + tid;         // f32x4 index within region [0,1600)
            if (idx < 1600) {
                const float* p0 = base + (size_t)idx * 4;
                f32x4 s = *(const f32x4*)p0;
#pragma unroll
                for (int kk = 1; kk < 8; ++kk) s += *(const f32x4*)(p0 + (size_t)kk * 25600);
                int f = idx >> 6, ln = idx & 63;
                int i = ((c >> 1) * 80) + (f / 5) * 16 + ((ln >> 4) << 2);
                int j = ((c & 1) * 80) + (f % 5) * 16 + (ln & 15);
                int gj = c0 + j;
                if (gj < A) {
#pragma unroll
                    for (int r = 0; r < 4; ++r) {
                        int gi = r0 + i + r;
                        if (gi < gj) local += s[r] * s[r];
                    }
                }
            }
        }
    }
#pragma unroll
    for (int o = 32; o > 0; o >>= 1) local += __shfl_down(local, o);
    __syncthreads();                          // ls reuse
    float* wred = (float*)ls;
    if (l == 0) wred[w] = local;
    __syncthreads();
    if (tid == 0) meta[16 + bid] = wred[0] + wred[1] + wred[2] + wred[3];
    // all 256 blocks write their slot unconditionally -> no zeroing needed

    gg.sync();                                // bsum complete, visible grid-wide

    // ======== phase 4: final loss (block 0) ========
    if (bid == 0) {
        float v = meta[16 + tid];
        #pragma unroll
        for (int o = 32; o > 0; o >>= 1) v += __shfl_down(v, o);
        __syncthreads();
        if (l == 0) wred[w] = v;
        __syncthreads();
        if (tid == 0) {
            float sq = wred[0] + wred[1] + wred[2] + wred[3];
            long long AA = A;
            long long na = AA * (AA - 1) / 2;
            double loss = 0.0;
            if (na > 0) loss = (double)sq / ((double)DDIM * (double)DDIM) / (double)na;
            out[0] = (float)loss;
        }
    }
}

extern "C" void kernel_launch(void* const* d_in, const int* in_sizes, int n_in,
                              void* d_out, int out_size, void* d_ws, size_t ws_size,
                              hipStream_t stream) {
    (void)in_sizes; (void)n_in; (void)out_size; (void)ws_size;
    const float* wgt  = (const float*)d_in[0];
    const float* mask = (const float*)d_in[1];
    float* out  = (float*)d_out;
    char*  ws   = (char*)d_ws;
    u16*   nf   = (u16*)(ws + NF_OFF);
    float* meta = (float*)ws;
    float* P    = (float*)(ws + P_OFF);

    void* args[] = {(void*)&wgt, (void*)&mask, (void*)&nf,
                    (void*)&meta, (void*)&P, (void*)&out};
    hipLaunchCooperativeKernel((const void*)mega_kernel, dim3(GRID), dim3(256),
                               args, 0u, stream);
}

// Round 8
// 174.719 us; speedup vs baseline: 1.4343x; 1.4343x over previous
//
#include <hip/hip_runtime.h>
#include <stdint.h>

#define NROWS 2048
#define DDIM  9216
#define TILE  160
#define NT160 13                      // ceil(2048/160) worst case
#define NTRI160 91                    // 13*14/2 worst-case triangle tiles
#define KS    8                       // K-slices (one per XCD)
#define KSLEN 1152                    // DDIM/KS
#define BK    64                      // K-step per stage
#define KIT   18                      // KSLEN/BK

typedef unsigned short u16;
typedef __bf16 bf16x8 __attribute__((ext_vector_type(8)));
typedef float  f32x4  __attribute__((ext_vector_type(4)));

// ws layout: meta[0..4096): [0] int cnt, [4] float sq, [8] int dcnt,
//                           [64..428) int tcnt[91]
//            [4096..) u16 nf[2048][9216]                    (37.75 MB)
//            [P_OFF..) float P[91][8][4][6400] partials     (74.5 MB max)
#define NF_OFF 4096ull
#define P_OFF  (NF_OFF + 2048ull * 9216ull * 2ull)

__device__ __forceinline__ u16 f2bf(float f) {
    uint32_t x = __float_as_uint(f);
    x += 0x7fffu + ((x >> 16) & 1u);          // round-to-nearest-even
    return (u16)(x >> 16);
}

__device__ __forceinline__ void gload16(const u16* g, u16* l) {
    __builtin_amdgcn_global_load_lds(
        (const __attribute__((address_space(1))) uint32_t*)g,
        (__attribute__((address_space(3))) uint32_t*)l, 16, 0, 0);
}

// ---------------- kernel 1: per-row stats + normalize + compact ----------------
__global__ __launch_bounds__(256) void stats_kernel(const float* __restrict__ wgt,
                                                    const float* __restrict__ mask,
                                                    u16* __restrict__ nf,
                                                    int* __restrict__ cnt) {
    int n = blockIdx.x;
    if (mask[n] == 0.0f) return;              // inactive filter: skip entirely
    int tid = threadIdx.x;
    const float4* row = (const float4*)(wgt + (size_t)n * DDIM);
    float4 v[9];
    float s = 0.f, ss = 0.f;
#pragma unroll
    for (int i = 0; i < 9; ++i) {
        v[i] = row[tid + 256 * i];
        s  += v[i].x + v[i].y + v[i].z + v[i].w;
        ss += v[i].x * v[i].x + v[i].y * v[i].y + v[i].z * v[i].z + v[i].w * v[i].w;
    }
#pragma unroll
    for (int o = 32; o > 0; o >>= 1) { s += __shfl_down(s, o); ss += __shfl_down(ss, o); }
    __shared__ float rs[4], rss[4];
    __shared__ float smean, sinv;
    __shared__ int   sidx;
    int w = tid >> 6, l = tid & 63;
    if (l == 0) { rs[w] = s; rss[w] = ss; }
    __syncthreads();
    if (tid == 0) {
        float S  = rs[0] + rs[1] + rs[2] + rs[3];
        float SS = rss[0] + rss[1] + rss[2] + rss[3];
        float mean = S / (float)DDIM;
        float var  = SS / (float)DDIM - mean * mean;
        float sd   = sqrtf(fmaxf(var, 0.f));
        if (sd == 0.f) sd = 1.f;              // reference: std==0 -> 1
        smean = mean; sinv = 1.f / sd;
        sidx = atomicAdd(cnt, 1);             // compacted slot (order irrelevant)
    }
    __syncthreads();
    float mean = smean, inv = sinv;
    u16* dst = nf + (size_t)sidx * DDIM;
#pragma unroll
    for (int i = 0; i < 9; ++i) {
        int e = (tid + 256 * i) * 4;
        uint32_t lo = (uint32_t)f2bf((v[i].x - mean) * inv) |
                      ((uint32_t)f2bf((v[i].y - mean) * inv) << 16);
        uint32_t hi = (uint32_t)f2bf((v[i].z - mean) * inv) |
                      ((uint32_t)f2bf((v[i].w - mean) * inv) << 16);
        uint2 u; u.x = lo; u.y = hi;
        *(uint2*)(dst + e) = u;
    }
}

// ---------------- kernel 2: 160x160-tile partial GEMM, K-split by 8 ----------------
// R6 core (proven): 224 active blocks <= 256 CUs, 4 waves x 80x80 quadrant,
// 3-buffer 2-deep pipeline, 120 KB LDS, one barrier per K-step, counted vmcnt.
// NEW (R8): fused split-K fixup. After the P store, each block does
// release-fence + per-tile arrival counter; the 8th arrival re-reads the
// tile's 8 partials (L2/L3-hot), squares/masks/sums, atomicAdds sq; a global
// tile counter lets the very last reducer compute the loss and write out[].
// Removes the reduce and final dispatches entirely.
template<bool DIAG>
__device__ __forceinline__ void stage(const u16* pA, const u16* pB, int kt,
                                      u16* buf, int w) {
    const u16* a = pA + kt * BK;
    u16* Ad = buf + w * 2560;                 // 40 rows x 64 u16 per wave
#pragma unroll
    for (int i = 0; i < 5; ++i)
        gload16(a + (size_t)(8 * i) * DDIM, Ad + i * 512);
    if (!DIAG) {
        const u16* b = pB + kt * BK;
        u16* Bd = buf + 10240 + w * 2560;     // B half of the stage buffer
#pragma unroll
        for (int i = 0; i < 5; ++i)
            gload16(b + (size_t)(8 * i) * DDIM, Bd + i * 512);
    }
}

template<bool DIAG>
__device__ __forceinline__ void compute(const u16* buf, int wr, int wc,
                                        int m16, int quad, f32x4 acc[5][5]) {
    const u16* Ab = buf;
    const u16* Bb = DIAG ? buf : buf + 10240;
#pragma unroll
    for (int kk = 0; kk < 2; ++kk) {
        int sw = ((((kk << 2) | quad) ^ (m16 & 7)) << 3);
        bf16x8 af[5], bfr[5];
#pragma unroll
        for (int fm = 0; fm < 5; ++fm)
            af[fm] = *(const bf16x8*)&Ab[(wr * 80 + fm * 16 + m16) * 64 + sw];
#pragma unroll
        for (int fn = 0; fn < 5; ++fn)
            bfr[fn] = *(const bf16x8*)&Bb[(wc * 80 + fn * 16 + m16) * 64 + sw];
#pragma unroll
        for (int fm = 0; fm < 5; ++fm)
#pragma unroll
            for (int fn = 0; fn < 5; ++fn)
                acc[fm][fn] = __builtin_amdgcn_mfma_f32_16x16x32_bf16(
                    af[fm], bfr[fn], acc[fm][fn], 0, 0, 0);
    }
}

__device__ __forceinline__ void barrier_fenced() {
    asm volatile("" ::: "memory");
    __builtin_amdgcn_s_barrier();
    asm volatile("" ::: "memory");
}

// one K-step: wait own stage(kt), barrier, prefetch stage(kt+2), compute(kt)
template<bool DIAG, bool PRE, int VM>
__device__ __forceinline__ void kstep(const u16* pA, const u16* pB, int kt,
                                      u16* bufC, u16* bufT, int w, int wr, int wc,
                                      int m16, int quad, bool dead, f32x4 acc[5][5]) {
    __builtin_amdgcn_s_waitcnt(VM);
    barrier_fenced();
    if (PRE) stage<DIAG>(pA, pB, kt + 2, bufT, w);
    if (!dead) compute<DIAG>(bufC, wr, wc, m16, quad, acc);
}

template<bool DIAG>
__device__ __forceinline__ void kloop(const u16* pA, const u16* pB, u16* ls,
                                      int w, int wr, int wc, int m16, int quad,
                                      bool dead, f32x4 acc[5][5]) {
    u16* b0 = ls;                             // 40 KB per stage buffer
    u16* b1 = ls + 20480;
    u16* b2 = ls + 40960;
    constexpr int VMF = DIAG ? 0x0F75 : 0x0F7A;   // vmcnt(5) / vmcnt(10)
    stage<DIAG>(pA, pB, 0, b0, w);
    stage<DIAG>(pA, pB, 1, b1, w);
    for (int kt = 0; kt < KIT - 3; kt += 3) {
        kstep<DIAG, true, VMF>(pA, pB, kt,     b0, b2, w, wr, wc, m16, quad, dead, acc);
        kstep<DIAG, true, VMF>(pA, pB, kt + 1, b1, b0, w, wr, wc, m16, quad, dead, acc);
        kstep<DIAG, true, VMF>(pA, pB, kt + 2, b2, b1, w, wr, wc, m16, quad, dead, acc);
    }
    kstep<DIAG, true,  VMF   >(pA, pB, KIT - 3, b0, b2, w, wr, wc, m16, quad, dead, acc);
    kstep<DIAG, false, VMF   >(pA, pB, KIT - 2, b1, b0, w, wr, wc, m16, quad, dead, acc);
    kstep<DIAG, false, 0x0F70>(pA, pB, KIT - 1, b2, b1, w, wr, wc, m16, quad, dead, acc);
}

__global__ __launch_bounds__(256) void gemm_kernel(const u16* __restrict__ nf,
                                                   int* __restrict__ meta,
                                                   float* __restrict__ P,
                                                   float* __restrict__ out) {
    __shared__ u16 ls[61440];                 // 120 KB: 3 x (A 20KB + B 20KB)
    __shared__ int sold;
    int A = meta[0];
    int nt = (A + TILE - 1) / TILE;
    int ntri = nt * (nt + 1) >> 1;
    int bid = blockIdx.x, tid = threadIdx.x;
    if (ntri == 0) {                          // A==0 edge: loss = 0
        if (bid == 0 && tid == 0) out[0] = 0.f;
        return;
    }
    int t = bid >> 3, k = bid & 7;            // k = bid%8 -> XCD k (round-robin)
    if (t >= ntri) return;                    // contiguous active prefix
    int tt = t, bi = 0, len = nt;
    while (tt >= len) { tt -= len; --len; ++bi; }
    int bj = bi + tt;                         // bi <= bj
    int r0 = bi * TILE, c0 = bj * TILE;
    int l = tid & 63, w = tid >> 6;
    int quad = l >> 4, m16 = l & 15;
    int wr = w >> 1, wc = w & 1;
    int colsw = ((l & 7) ^ (l >> 3)) << 3;    // pre-swizzled global col chunk
    size_t kbase = (size_t)k * KSLEN + colsw;
    const u16* pA = nf + (size_t)(r0 + 40 * w + (l >> 3)) * DDIM + kbase;
    const u16* pB = nf + (size_t)(c0 + 40 * w + (l >> 3)) * DDIM + kbase;
    bool dead = (bi == bj) && (w == 2);       // diag sub-block, all gi>gj
    f32x4 acc[5][5] = {};
    if (bi == bj) kloop<true >(pA, pB, ls, w, wr, wc, m16, quad, dead, acc);
    else          kloop<false>(pA, pB, ls, w, wr, wc, m16, quad, dead, acc);
    // frag-major coalesced partial store: P[(t*8+k)*4 + w][frag][lane][reg]
    float* dst = P + ((size_t)(t * 8 + k) * 4 + w) * 6400;
#pragma unroll
    for (int fm = 0; fm < 5; ++fm)
#pragma unroll
        for (int fn = 0; fn < 5; ++fn)
            *(f32x4*)&dst[(fm * 5 + fn) * 256 + l * 4] = acc[fm][fn];

    // ---- fused split-K fixup: release fence + per-tile arrival counter ----
    __syncthreads();                          // all waves' stores drained to L2
    if (tid == 0) {
        __threadfence();                      // device-scope release (L2 wb)
        sold = atomicAdd(&meta[16 + t], 1);
    }
    __syncthreads();
    if (sold == KS - 1) {                     // last arrival reduces tile t
        __threadfence();                      // acquire: drop stale L2 lines
        const float* base = P + (size_t)t * 204800;
        float local = 0.f;
        for (int V = tid; V < 6400; V += 256) {   // f32x4 index within tile
            int c = V / 1600, idx = V - c * 1600;
            const float* p0 = base + (size_t)c * 6400 + (size_t)idx * 4;
            f32x4 s = *(const f32x4*)p0;
#pragma unroll
            for (int kk = 1; kk < 8; ++kk) s += *(const f32x4*)(p0 + (size_t)kk * 25600);
            int f = idx >> 6, ln = idx & 63;
            int i = ((c >> 1) * 80) + (f / 5) * 16 + ((ln >> 4) << 2);
            int j = ((c & 1) * 80) + (f % 5) * 16 + (ln & 15);
            int gj = c0 + j;
            if (gj < A) {
#pragma unroll
                for (int r = 0; r < 4; ++r) {
                    int gi = r0 + i + r;
                    if (gi < gj) local += s[r] * s[r];
                }
            }
        }
#pragma unroll
        for (int o = 32; o > 0; o >>= 1) local += __shfl_down(local, o);
        if (l == 0) atomicAdd((float*)meta + 1, local);   // sq
        __syncthreads();                      // sq adds drained
        if (tid == 0) {
            __threadfence();                  // order sq adds before dcnt bump
            int old = atomicAdd(&meta[2], 1);
            if (old == ntri - 1) {            // very last tile: finalize loss
                float s = atomicAdd((float*)meta + 1, 0.f);   // coherent read
                long long AA = A;
                long long na = AA * (AA - 1) / 2;
                double loss = 0.0;
                if (na > 0) loss = (double)s / ((double)DDIM * (double)DDIM) / (double)na;
                out[0] = (float)loss;
            }
        }
    }
}

extern "C" void kernel_launch(void* const* d_in, const int* in_sizes, int n_in,
                              void* d_out, int out_size, void* d_ws, size_t ws_size,
                              hipStream_t stream) {
    (void)in_sizes; (void)n_in; (void)out_size; (void)ws_size;
    const float* wgt  = (const float*)d_in[0];
    const float* mask = (const float*)d_in[1];
    float* out = (float*)d_out;
    char*  ws  = (char*)d_ws;

    int*   meta = (int*)ws;                   // cnt, sq, dcnt, tcnt[91]
    u16*   nf   = (u16*)(ws + NF_OFF);
    float* P    = (float*)(ws + P_OFF);

    hipMemsetAsync(ws, 0, 4096, stream);
    stats_kernel<<<NROWS, 256, 0, stream>>>(wgt, mask, nf, meta);
    gemm_kernel<<<NTRI160 * KS, 256, 0, stream>>>(nf, meta, P, out);
}

// Round 9
// 133.879 us; speedup vs baseline: 1.8719x; 1.3051x over previous
//
#include <hip/hip_runtime.h>
#include <stdint.h>

#define NROWS 2048
#define DDIM  9216
#define TILE  160
#define NT160 13                      // ceil(2048/160) worst case
#define NTRI160 91                    // 13*14/2 worst-case triangle tiles
#define KS    8                       // K-slices (one per XCD)
#define KSLEN 1152                    // DDIM/KS
#define BK    64                      // K-step per stage
#define KIT   18                      // KSLEN/BK

typedef unsigned short u16;
typedef __bf16 bf16x8 __attribute__((ext_vector_type(8)));
typedef float  f32x4  __attribute__((ext_vector_type(4)));

// ws layout: meta[0..4096): [0] int A, [4] float sq, [8] int dcnt
//            [4096..) u16 nf[2048][9216]                    (37.75 MB)
//            [P_OFF..) float P[91][8][4][6400] partials     (74.5 MB max)
#define NF_OFF 4096ull
#define P_OFF  (NF_OFF + 2048ull * 9216ull * 2ull)

__device__ __forceinline__ u16 f2bf(float f) {
    uint32_t x = __float_as_uint(f);
    x += 0x7fffu + ((x >> 16) & 1u);          // round-to-nearest-even
    return (u16)(x >> 16);
}

__device__ __forceinline__ void gload16(const u16* g, u16* l) {
    __builtin_amdgcn_global_load_lds(
        (const __attribute__((address_space(1))) uint32_t*)g,
        (__attribute__((address_space(3))) uint32_t*)l, 16, 0, 0);
}

// ---------------- kernel 1: census + per-row stats + normalize + compact --------
// No memset dependency: compaction slot = #active rows with index < n, computed
// by an 8 KB L2-hot census of the mask per block (replaces the cnt atomic).
// Block 0 publishes A and zeroes sq/dcnt for the reduce dispatch (race-free:
// consumers are later dispatches on the same stream).
__global__ __launch_bounds__(256) void stats_kernel(const float* __restrict__ wgt,
                                                    const float* __restrict__ mask,
                                                    u16* __restrict__ nf,
                                                    int* __restrict__ meta) {
    int n = blockIdx.x, tid = threadIdx.x;
    int w = tid >> 6, l = tid & 63;
    int c_pre = 0, c_tot = 0;                 // census: actives before n / total
#pragma unroll
    for (int r = 0; r < 8; ++r) {
        int j = tid * 8 + r;
        int a = (mask[j] != 0.0f) ? 1 : 0;
        c_tot += a;
        if (j < n) c_pre += a;
    }
#pragma unroll
    for (int o = 32; o > 0; o >>= 1) {
        c_pre += __shfl_down(c_pre, o);
        c_tot += __shfl_down(c_tot, o);
    }
    __shared__ int sp[4], st[4];
    __shared__ float rs[4], rss[4], smean, sinv;
    if (l == 0) { sp[w] = c_pre; st[w] = c_tot; }
    __syncthreads();
    int slot = sp[0] + sp[1] + sp[2] + sp[3];
    if (n == 0 && tid == 0) {
        meta[0] = st[0] + st[1] + st[2] + st[3];  // A
        meta[1] = 0;                              // sq (float 0.0 bits)
        meta[2] = 0;                              // dcnt
    }
    if (mask[n] == 0.0f) return;              // block-uniform: syncs below safe
    const float4* row = (const float4*)(wgt + (size_t)n * DDIM);
    float4 v[9];
    float s = 0.f, ss = 0.f;
#pragma unroll
    for (int i = 0; i < 9; ++i) {
        v[i] = row[tid + 256 * i];
        s  += v[i].x + v[i].y + v[i].z + v[i].w;
        ss += v[i].x * v[i].x + v[i].y * v[i].y + v[i].z * v[i].z + v[i].w * v[i].w;
    }
#pragma unroll
    for (int o = 32; o > 0; o >>= 1) { s += __shfl_down(s, o); ss += __shfl_down(ss, o); }
    if (l == 0) { rs[w] = s; rss[w] = ss; }
    __syncthreads();
    if (tid == 0) {
        float S  = rs[0] + rs[1] + rs[2] + rs[3];
        float SS = rss[0] + rss[1] + rss[2] + rss[3];
        float mean = S / (float)DDIM;
        float var  = SS / (float)DDIM - mean * mean;
        float sd   = sqrtf(fmaxf(var, 0.f));
        if (sd == 0.f) sd = 1.f;              // reference: std==0 -> 1
        smean = mean; sinv = 1.f / sd;
    }
    __syncthreads();
    float mean = smean, inv = sinv;
    u16* dst = nf + (size_t)slot * DDIM;
#pragma unroll
    for (int i = 0; i < 9; ++i) {
        int e = (tid + 256 * i) * 4;
        uint32_t lo = (uint32_t)f2bf((v[i].x - mean) * inv) |
                      ((uint32_t)f2bf((v[i].y - mean) * inv) << 16);
        uint32_t hi = (uint32_t)f2bf((v[i].z - mean) * inv) |
                      ((uint32_t)f2bf((v[i].w - mean) * inv) << 16);
        uint2 u; u.x = lo; u.y = hi;
        *(uint2*)(dst + e) = u;
    }
}

// ---------------- kernel 2: 160x160-tile partial GEMM, K-split by 8 ----------------
// R6 core verbatim (proven): 224 active blocks <= 256 CUs, 4 waves x 80x80
// quadrant, 3-buffer 2-deep pipeline, 120 KB LDS, one barrier per K-step,
// counted vmcnt. NO in-kernel fixup (R8 lesson: intra-kernel grid visibility
// costs an L2 flush per block; dispatch-boundary coherence is free).
template<bool DIAG>
__device__ __forceinline__ void stage(const u16* pA, const u16* pB, int kt,
                                      u16* buf, int w) {
    const u16* a = pA + kt * BK;
    u16* Ad = buf + w * 2560;                 // 40 rows x 64 u16 per wave
#pragma unroll
    for (int i = 0; i < 5; ++i)
        gload16(a + (size_t)(8 * i) * DDIM, Ad + i * 512);
    if (!DIAG) {
        const u16* b = pB + kt * BK;
        u16* Bd = buf + 10240 + w * 2560;     // B half of the stage buffer
#pragma unroll
        for (int i = 0; i < 5; ++i)
            gload16(b + (size_t)(8 * i) * DDIM, Bd + i * 512);
    }
}

template<bool DIAG>
__device__ __forceinline__ void compute(const u16* buf, int wr, int wc,
                                        int m16, int quad, f32x4 acc[5][5]) {
    const u16* Ab = buf;
    const u16* Bb = DIAG ? buf : buf + 10240;
#pragma unroll
    for (int kk = 0; kk < 2; ++kk) {
        int sw = ((((kk << 2) | quad) ^ (m16 & 7)) << 3);
        bf16x8 af[5], bfr[5];
#pragma unroll
        for (int fm = 0; fm < 5; ++fm)
            af[fm] = *(const bf16x8*)&Ab[(wr * 80 + fm * 16 + m16) * 64 + sw];
#pragma unroll
        for (int fn = 0; fn < 5; ++fn)
            bfr[fn] = *(const bf16x8*)&Bb[(wc * 80 + fn * 16 + m16) * 64 + sw];
#pragma unroll
        for (int fm = 0; fm < 5; ++fm)
#pragma unroll
            for (int fn = 0; fn < 5; ++fn)
                acc[fm][fn] = __builtin_amdgcn_mfma_f32_16x16x32_bf16(
                    af[fm], bfr[fn], acc[fm][fn], 0, 0, 0);
    }
}

__device__ __forceinline__ void barrier_fenced() {
    asm volatile("" ::: "memory");
    __builtin_amdgcn_s_barrier();
    asm volatile("" ::: "memory");
}

template<bool DIAG, bool PRE, int VM>
__device__ __forceinline__ void kstep(const u16* pA, const u16* pB, int kt,
                                      u16* bufC, u16* bufT, int w, int wr, int wc,
                                      int m16, int quad, bool dead, f32x4 acc[5][5]) {
    __builtin_amdgcn_s_waitcnt(VM);
    barrier_fenced();
    if (PRE) stage<DIAG>(pA, pB, kt + 2, bufT, w);
    if (!dead) compute<DIAG>(bufC, wr, wc, m16, quad, acc);
}

template<bool DIAG>
__device__ __forceinline__ void kloop(const u16* pA, const u16* pB, u16* ls,
                                      int w, int wr, int wc, int m16, int quad,
                                      bool dead, f32x4 acc[5][5]) {
    u16* b0 = ls;                             // 40 KB per stage buffer
    u16* b1 = ls + 20480;
    u16* b2 = ls + 40960;
    constexpr int VMF = DIAG ? 0x0F75 : 0x0F7A;   // vmcnt(5) / vmcnt(10)
    stage<DIAG>(pA, pB, 0, b0, w);
    stage<DIAG>(pA, pB, 1, b1, w);
    for (int kt = 0; kt < KIT - 3; kt += 3) {
        kstep<DIAG, true, VMF>(pA, pB, kt,     b0, b2, w, wr, wc, m16, quad, dead, acc);
        kstep<DIAG, true, VMF>(pA, pB, kt + 1, b1, b0, w, wr, wc, m16, quad, dead, acc);
        kstep<DIAG, true, VMF>(pA, pB, kt + 2, b2, b1, w, wr, wc, m16, quad, dead, acc);
    }
    kstep<DIAG, true,  VMF   >(pA, pB, KIT - 3, b0, b2, w, wr, wc, m16, quad, dead, acc);
    kstep<DIAG, false, VMF   >(pA, pB, KIT - 2, b1, b0, w, wr, wc, m16, quad, dead, acc);
    kstep<DIAG, false, 0x0F70>(pA, pB, KIT - 1, b2, b1, w, wr, wc, m16, quad, dead, acc);
}

__global__ __launch_bounds__(256) void gemm_kernel(const u16* __restrict__ nf,
                                                   const int* __restrict__ meta,
                                                   float* __restrict__ P) {
    __shared__ u16 ls[61440];                 // 120 KB: 3 x (A 20KB + B 20KB)
    int A = meta[0];
    int nt = (A + TILE - 1) / TILE;
    int ntri = nt * (nt + 1) >> 1;
    int bid = blockIdx.x;
    int t = bid >> 3, k = bid & 7;            // k = bid%8 -> XCD k (round-robin)
    if (t >= ntri) return;                    // contiguous active prefix
    int tt = t, bi = 0, len = nt;
    while (tt >= len) { tt -= len; --len; ++bi; }
    int bj = bi + tt;                         // bi <= bj
    int r0 = bi * TILE, c0 = bj * TILE;
    int tid = threadIdx.x, l = tid & 63, w = tid >> 6;
    int quad = l >> 4, m16 = l & 15;
    int wr = w >> 1, wc = w & 1;
    int colsw = ((l & 7) ^ (l >> 3)) << 3;    // pre-swizzled global col chunk
    size_t kbase = (size_t)k * KSLEN + colsw;
    const u16* pA = nf + (size_t)(r0 + 40 * w + (l >> 3)) * DDIM + kbase;
    const u16* pB = nf + (size_t)(c0 + 40 * w + (l >> 3)) * DDIM + kbase;
    bool dead = (bi == bj) && (w == 2);       // diag sub-block, all gi>gj
    f32x4 acc[5][5] = {};
    if (bi == bj) kloop<true >(pA, pB, ls, w, wr, wc, m16, quad, dead, acc);
    else          kloop<false>(pA, pB, ls, w, wr, wc, m16, quad, dead, acc);
    // frag-major coalesced partial store: P[(t*8+k)*4 + w][frag][lane][reg]
    float* dst = P + ((size_t)(t * 8 + k) * 4 + w) * 6400;
#pragma unroll
    for (int fm = 0; fm < 5; ++fm)
#pragma unroll
        for (int fn = 0; fn < 5; ++fn)
            *(f32x4*)&dst[(fm * 5 + fn) * 256 + l * 4] = acc[fm][fn];
}

// ---------------- kernel 3: reduce 8 k-partials + fused finalize ----------------
// R6 reduce + last-arrival finalize using ATOMICS ONLY (no threadfence / L2
// flush): atomicAdd(sq) in returning form + explicit vmcnt(0) guarantees the
// sq update reached the coherence point before the dcnt bump; the last block
// re-reads sq via atomicAdd(sq, 0) and writes the loss. Removes final_kernel.
__global__ __launch_bounds__(256) void reduce_kernel(const float* __restrict__ P,
                                                     int* __restrict__ meta,
                                                     float* __restrict__ out) {
    int A = meta[0];
    int nt = (A + TILE - 1) / TILE;
    int ntri = nt * (nt + 1) >> 1;
    int tid = threadIdx.x, l = tid & 63, w = tid >> 6;
    if (ntri == 0) {                          // A==0 edge: loss = 0
        if (blockIdx.x == 0 && tid == 0) out[0] = 0.f;
        return;
    }
    int t = blockIdx.x >> 2, c = blockIdx.x & 3;
    if (t >= ntri) return;
    int tt = t, bi = 0, len = nt;             // SAME nt-triangle mapping as gemm
    while (tt >= len) { tt -= len; --len; ++bi; }
    int bj = bi + tt;
    int r0 = bi * TILE, c0 = bj * TILE;
    const float* base = P + (size_t)t * 204800 + (size_t)c * 6400;
    float local = 0.f;
#pragma unroll
    for (int mm = 0; mm < 7; ++mm) {
        int idx = mm * 256 + tid;             // f32x4 index within region [0,1600)
        if (idx < 1600) {
            const float* p0 = base + (size_t)idx * 4;
            f32x4 s = *(const f32x4*)p0;
#pragma unroll
            for (int kk = 1; kk < 8; ++kk) s += *(const f32x4*)(p0 + (size_t)kk * 25600);
            int f = idx >> 6, ln = idx & 63;
            int i = ((c >> 1) * 80) + (f / 5) * 16 + ((ln >> 4) << 2);
            int j = ((c & 1) * 80) + (f % 5) * 16 + (ln & 15);
            int gj = c0 + j;
            if (gj < A) {
#pragma unroll
                for (int r = 0; r < 4; ++r) {
                    int gi = r0 + i + r;
                    if (gi < gj) local += s[r] * s[r];
                }
            }
        }
    }
#pragma unroll
    for (int o = 32; o > 0; o >>= 1) local += __shfl_down(local, o);
    __shared__ float wred[4];
    if (l == 0) wred[w] = local;
    __syncthreads();
    if (tid == 0) {
        float bsum = wred[0] + wred[1] + wred[2] + wred[3];
        float* sqp = (float*)(meta + 1);
        float oldsq = atomicAdd(sqp, bsum);   // returning form -> tracked by vmcnt
        asm volatile("s_waitcnt vmcnt(0)" :: "v"(oldsq) : "memory");
        int oldc = atomicAdd(meta + 2, 1);    // ordered after sq at coherence pt
        if (oldc == ntri * 4 - 1) {           // last arrival: finalize loss
            float s = atomicAdd(sqp, 0.0f);   // coherent read of the full sum
            long long AA = A;
            long long na = AA * (AA - 1) / 2;
            double loss = 0.0;
            if (na > 0) loss = (double)s / ((double)DDIM * (double)DDIM) / (double)na;
            out[0] = (float)loss;
        }
    }
}

extern "C" void kernel_launch(void* const* d_in, const int* in_sizes, int n_in,
                              void* d_out, int out_size, void* d_ws, size_t ws_size,
                              hipStream_t stream) {
    (void)in_sizes; (void)n_in; (void)out_size; (void)ws_size;
    const float* wgt  = (const float*)d_in[0];
    const float* mask = (const float*)d_in[1];
    float* out = (float*)d_out;
    char*  ws  = (char*)d_ws;

    int*   meta = (int*)ws;                   // A, sq, dcnt (zeroed by stats blk 0)
    u16*   nf   = (u16*)(ws + NF_OFF);
    float* P    = (float*)(ws + P_OFF);

    stats_kernel<<<NROWS, 256, 0, stream>>>(wgt, mask, nf, meta);
    gemm_kernel<<<NTRI160 * KS, 256, 0, stream>>>(nf, meta, P);
    reduce_kernel<<<NTRI160 * 4, 256, 0, stream>>>(P, meta, out);
}